// Round 8
// baseline (512.670 us; speedup 1.0000x reference)
//
#include <hip/hip_runtime.h>
#include <hip/hip_fp16.h>

#define N_NODES 4096
#define N_GRAPHS 32
#define NTOT (N_NODES * N_GRAPHS)   // 131072
#define NE (NTOT * 32)              // 4194304 edges
#define C1 16
#define C2 20
#define CAP 72                       // max in-degree capacity (Poisson(32) tail @72 ~5e-10/node)

// bucket-sort build parameters
#define NBUCK 512                    // dst buckets (256 nodes each)
#define BSHIFT 8
#define BMASK 255
#define CAPB 8960                    // records per bucket region (mean 8192, +8.5 sigma)
#define EPB1 8192                    // edges per pass-1 block (512 blocks total)

__device__ __forceinline__ float lrelu(float v) { return v > 0.f ? v : 0.01f * v; }

// ---- edge pack: src (17 bits) | w quantized to 15-bit fixed point in [0,1) ----
__device__ __forceinline__ unsigned pack_edge(int src, float w) {
    int k = __float2int_rn(w * 32768.f);
    if (k > 32767) k = 32767;
    return (unsigned)src | ((unsigned)k << 17);
}
__device__ __forceinline__ void unpack_edge(unsigned p, int& src, float& w) {
    src = (int)(p & 0x1FFFFu);
    w = (float)(p >> 17) * 3.0517578125e-5f;   // /32768
}

// ---- fp16 pack/unpack/fma helpers ----
__device__ __forceinline__ uint4 pack8h(const float* v) {
    union { uint4 u4; __half h[8]; } c;
#pragma unroll
    for (int q = 0; q < 8; q++) c.h[q] = __float2half(v[q]);
    return c.u4;
}
__device__ __forceinline__ uint2 pack4h(const float* v) {
    union { uint2 u2; __half h[4]; } c;
#pragma unroll
    for (int q = 0; q < 4; q++) c.h[q] = __float2half(v[q]);
    return c.u2;
}
__device__ __forceinline__ void fma8(uint4 u, float wv, float* acc) {
    union { uint4 u4; __half2 h2[4]; } c; c.u4 = u;
#pragma unroll
    for (int q = 0; q < 4; q++) {
        float2 f = __half22float2(c.h2[q]);
        acc[2 * q]     += f.x * wv;
        acc[2 * q + 1] += f.y * wv;
    }
}
__device__ __forceinline__ void fma4(uint2 u, float wv, float* acc) {
    union { uint2 u2; __half2 h2[2]; } c; c.u2 = u;
#pragma unroll
    for (int q = 0; q < 2; q++) {
        float2 f = __half22float2(c.h2[q]);
        acc[2 * q]     += f.x * wv;
        acc[2 * q + 1] += f.y * wv;
    }
}
__device__ __forceinline__ void unp8(uint4 u, float* v) {
    union { uint4 u4; __half2 h2[4]; } c; c.u4 = u;
#pragma unroll
    for (int q = 0; q < 4; q++) {
        float2 f = __half22float2(c.h2[q]);
        v[2 * q] = f.x; v[2 * q + 1] = f.y;
    }
}
__device__ __forceinline__ void unp4(uint2 u, float* v) {
    union { uint2 u2; __half2 h2[2]; } c; c.u2 = u;
#pragma unroll
    for (int q = 0; q < 2; q++) {
        float2 f = __half22float2(c.h2[q]);
        v[2 * q] = f.x; v[2 * q + 1] = f.y;
    }
}

// ---- gather phases: 8-deep unrolled slot->gather->fma chains ----
__device__ __forceinline__ void gather16(const uint4* __restrict__ arr,
                                         const unsigned* __restrict__ slots,
                                         int gn, int lo, int hi, float* acc) {
    int i = lo;
    for (; i + 8 <= hi; i += 8) {
        unsigned p[8];
#pragma unroll
        for (int k = 0; k < 8; k++) p[k] = __builtin_nontemporal_load(slots + (size_t)(i + k) * NTOT + gn);
        uint4 u[8]; float w[8];
#pragma unroll
        for (int k = 0; k < 8; k++) { int s; unpack_edge(p[k], s, w[k]); u[k] = arr[s]; }
#pragma unroll
        for (int k = 0; k < 8; k++) fma8(u[k], w[k], acc);
    }
    for (; i < hi; i++) {
        unsigned p = __builtin_nontemporal_load(slots + (size_t)i * NTOT + gn);
        int s; float w; unpack_edge(p, s, w);
        fma8(arr[s], w, acc);
    }
}
__device__ __forceinline__ void gather8(const uint2* __restrict__ arr,
                                        const unsigned* __restrict__ slots,
                                        int gn, int lo, int hi, float* acc) {
    int i = lo;
    for (; i + 8 <= hi; i += 8) {
        unsigned p[8];
#pragma unroll
        for (int k = 0; k < 8; k++) p[k] = __builtin_nontemporal_load(slots + (size_t)(i + k) * NTOT + gn);
        uint2 u[8]; float w[8];
#pragma unroll
        for (int k = 0; k < 8; k++) { int s; unpack_edge(p[k], s, w[k]); u[k] = arr[s]; }
#pragma unroll
        for (int k = 0; k < 8; k++) fma4(u[k], w[k], acc);
    }
    for (; i < hi; i++) {
        unsigned p = __builtin_nontemporal_load(slots + (size_t)i * NTOT + gn);
        int s; float w; unpack_edge(p, s, w);
        fma4(arr[s], w, acc);
    }
}

// ======================= build pass 1: LDS counting sort per 8192-edge tile =======================
__global__ __launch_bounds__(256) void k_part1(const int* __restrict__ ei,
                                               const float* __restrict__ ea,
                                               int* __restrict__ gcur,
                                               uint2* __restrict__ part) {
    __shared__ unsigned lrecA[EPB1];          // packed (src|w)      32 KB
    __shared__ unsigned char lrecB[EPB1];     // local dst (8 bits)   8 KB
    __shared__ int hist[NBUCK], sscan[NBUCK], base[NBUCK], lcur[NBUCK];  // 8 KB
    __shared__ int ts[256];                   // 1 KB
    int t = threadIdx.x;
    hist[t] = 0; hist[t + 256] = 0;
    __syncthreads();
    int eb = blockIdx.x * EPB1;
    int dreg[EPB1 / 256];
#pragma unroll
    for (int i = 0; i < EPB1 / 256; i++) {
        int d = ei[NE + eb + i * 256 + t];
        dreg[i] = d;
        atomicAdd(&hist[d >> BSHIFT], 1);
    }
    __syncthreads();
    // block-exclusive scan of hist[512] with 256 threads
    int a0 = hist[2 * t], a1 = hist[2 * t + 1];
    ts[t] = a0 + a1;
    __syncthreads();
    for (int d = 1; d < 256; d <<= 1) {
        int v = (t >= d) ? ts[t - d] : 0;
        __syncthreads();
        ts[t] += v;
        __syncthreads();
    }
    int excl = (t == 0) ? 0 : ts[t - 1];
    sscan[2 * t] = excl;
    sscan[2 * t + 1] = excl + a0;
    lcur[2 * t] = excl;
    lcur[2 * t + 1] = excl + a0;
    base[t]       = atomicAdd(&gcur[t], hist[t]);
    base[t + 256] = atomicAdd(&gcur[t + 256], hist[t + 256]);
    __syncthreads();
    // scatter records into LDS in bucket order
#pragma unroll
    for (int i = 0; i < EPB1 / 256; i++) {
        int e = eb + i * 256 + t;
        int d = dreg[i];
        int b = d >> BSHIFT;
        int pos = atomicAdd(&lcur[b], 1);
        lrecA[pos] = pack_edge(ei[e], ea[3 * e + 2]);
        lrecB[pos] = (unsigned char)(d & BMASK);
    }
    __syncthreads();
    // stream out: consecutive j -> same bucket -> consecutive global addresses
    for (int j = t; j < EPB1; j += 256) {
        int lo = 0, hi = NBUCK - 1;
        while (lo < hi) { int mid = (lo + hi + 1) >> 1; if (sscan[mid] <= j) lo = mid; else hi = mid - 1; }
        int b = lo;
        int dp = base[b] + (j - sscan[b]);
        if (dp < CAPB) part[(size_t)b * CAPB + dp] = make_uint2(lrecA[j], (unsigned)lrecB[j]);
    }
}

// ======================= build pass 2 v2: LDS tile + coalesced slot writes =======================
// block = half-bucket (128 nodes); scatter into LDS tile, stream out row-major.
__global__ __launch_bounds__(256) void k_part2(const int* __restrict__ gcur,
                                               const uint2* __restrict__ part,
                                               unsigned* __restrict__ slots,
                                               int* __restrict__ cnt) {
    __shared__ unsigned tile[128 * CAP];      // 36.9 KB, layout [pos][l]
    __shared__ int cur[128];
    __shared__ int maxc;
    int t = threadIdx.x;
    if (t < 128) cur[t] = 0;
    if (t == 0) maxc = 0;
    __syncthreads();
    int b = blockIdx.x >> 1;
    int halfsel = blockIdx.x & 1;
    int nbase = (b << BSHIFT) + (halfsel << 7);
    int nrec = gcur[b]; if (nrec > CAPB) nrec = CAPB;
    const uint2* rp = part + (size_t)b * CAPB;
    for (int i = t; i < nrec; i += 256) {
        uint2 r = rp[i];
        int ld = (int)r.y;
        if ((ld >> 7) == halfsel) {
            int l = ld & 127;
            int pos = atomicAdd(&cur[l], 1);
            if (pos < CAP) tile[pos * 128 + l] = r.x;
        }
    }
    __syncthreads();
    if (t < 128) { cnt[nbase + t] = cur[t]; atomicMax(&maxc, cur[t]); }
    __syncthreads();
    int mc = maxc; if (mc > CAP) mc = CAP;
    for (int j = t; j < mc * 128; j += 256) {
        int pos = j >> 7, l = j & 127;
        slots[(size_t)pos * NTOT + nbase + l] = tile[j];
    }
}

// ======================= fallback build: single-atomic slot fill =======================
__global__ void k_fill_slots(const int* __restrict__ ei, const float* __restrict__ ea,
                             int* __restrict__ cnt, unsigned* __restrict__ slots) {
    int e = blockIdx.x * 256 + threadIdx.x;
    if (e >= NE) return;
    int d = ei[NE + e];
    int pos = atomicAdd(&cnt[d], 1);
    if (pos < CAP) slots[(size_t)pos * NTOT + d] = pack_edge(ei[e], ea[3 * e + 2]);
}

// ---------------- x -> fp16 split arrays (ch0-7, ch8-15) ----------------
__global__ void k_xcast(const float* __restrict__ x, uint4* __restrict__ xa, uint4* __restrict__ xb) {
    int n = blockIdx.x * 256 + threadIdx.x;
    if (n >= NTOT) return;
    float xr[C1];
    const float4* xp = (const float4*)(x + (size_t)n * C1);
#pragma unroll
    for (int q = 0; q < 4; q++) ((float4*)xr)[q] = xp[q];
    xa[n] = pack8h(xr);
    xb[n] = pack8h(xr + 8);
}

// ---------------- conv1: 2-way edge split, SEQUENTIAL channel phases (xa then xb) ----------------
__global__ __launch_bounds__(256) void k_conv1(const uint4* __restrict__ xa, const uint4* __restrict__ xb,
                        const unsigned* __restrict__ slots, const int* __restrict__ cnt,
                        const float* __restrict__ Wr, const float* __restrict__ bb,
                        const float* __restrict__ Wo, float* __restrict__ t1) {
    __shared__ float sWr[C1 * C2], sWo[C1 * C2], sb[C2];
    __shared__ float sacc[2][128][17];   // +1 pad: conflict-free
    for (int k = threadIdx.x; k < C1 * C2; k += 256) { sWr[k] = Wr[k]; sWo[k] = Wo[k]; }
    if (threadIdx.x < C2) sb[threadIdx.x] = bb[threadIdx.x];
    int nl = threadIdx.x & 127;
    int half = threadIdx.x >> 7;          // wave-uniform
    int gn = blockIdx.x * 128 + nl;
    int m = cnt[gn]; if (m > CAP) m = CAP;
    int h0 = m >> 1;
    int lo = half ? h0 : 0;
    int hi = half ? m : h0;
    float acc[C1];
#pragma unroll
    for (int q = 0; q < C1; q++) acc[q] = 0.f;
    gather16(xa, slots, gn, lo, hi, acc);       // phase A: ch 0-7 (2.1 MB hot)
    gather16(xb, slots, gn, lo, hi, acc + 8);   // phase B: ch 8-15
#pragma unroll
    for (int q = 0; q < C1; q++) sacc[half][nl][q] = acc[q];
    __syncthreads();
    // epilogue: thread -> (node n2, output half oh) : 10 outputs each
    int n2 = threadIdx.x >> 1, oh = threadIdx.x & 1;
    int gn2 = blockIdx.x * 128 + n2;
    float accf[C1];
#pragma unroll
    for (int q = 0; q < C1; q++) accf[q] = sacc[0][n2][q] + sacc[1][n2][q];
    float xr[C1];
    unp8(xa[gn2], xr); unp8(xb[gn2], xr + 8);
    float outv[10];
#pragma unroll
    for (int jj = 0; jj < 10; jj++) {
        int j = oh * 10 + jj;
        float a = sb[j];
#pragma unroll
        for (int q = 0; q < C1; q++) a += accf[q] * sWr[q * C2 + j] + xr[q] * sWo[q * C2 + j];
        outv[jj] = lrelu(a);
    }
#pragma unroll
    for (int jj = 0; jj < 10; jj++) t1[(size_t)gn2 * C2 + oh * 10 + jj] = outv[jj];
}

// ---------------- BN stats: per node-index i over 32 graphs x 20 ch (fp32 t) ----------------
__global__ void k_stats(const float* __restrict__ t, float* __restrict__ mu, float* __restrict__ rs) {
    int i = blockIdx.x;
    float s = 0.f, ss = 0.f;
    for (int k = threadIdx.x; k < N_GRAPHS * C2; k += 64) {
        int g = k / C2, j = k - g * C2;
        float v = t[((size_t)(g * N_NODES + i)) * C2 + j];
        s += v; ss += v * v;
    }
#pragma unroll
    for (int off = 32; off > 0; off >>= 1) { s += __shfl_down(s, off); ss += __shfl_down(ss, off); }
    if (threadIdx.x == 0) {
        float m = s * (1.f / (N_GRAPHS * C2));
        float var = ss * (1.f / (N_GRAPHS * C2)) - m * m;
        mu[i] = m;
        rs[i] = rsqrtf(var + 1e-5f);
    }
}

// ---------------- BN apply -> fp16 split hn: hnA ch0-7, hnB1 ch8-15, hnB2 ch16-19 ----------------
__global__ void k_bn_apply(const float* __restrict__ t, const float* __restrict__ mu,
                           const float* __restrict__ rs, const float* __restrict__ gam,
                           const float* __restrict__ bet, uint4* __restrict__ hnA,
                           uint4* __restrict__ hnB1, uint2* __restrict__ hnB2) {
    int n = blockIdx.x * 256 + threadIdx.x;
    if (n >= NTOT) return;
    int i = n & (N_NODES - 1);
    float sc = rs[i] * gam[i];
    float sh = bet[i] - mu[i] * sc;
    float v[C2];
    const float4* tp = (const float4*)(t + (size_t)n * C2);
#pragma unroll
    for (int q = 0; q < 5; q++) ((float4*)v)[q] = tp[q];
#pragma unroll
    for (int j = 0; j < C2; j++) v[j] = v[j] * sc + sh;
    hnA[n] = pack8h(v);
    hnB1[n] = pack8h(v + 8);
    hnB2[n] = pack4h(v + 16);
}

// ---------------- conv2: 2-way edge split, SEQUENTIAL phases (hnA, hnB1, hnB2) ----------------
__global__ __launch_bounds__(256) void k_conv2(const uint4* __restrict__ hnA,
                        const uint4* __restrict__ hnB1, const uint2* __restrict__ hnB2,
                        const unsigned* __restrict__ slots, const int* __restrict__ cnt,
                        const float* __restrict__ Wr, const float* __restrict__ bb,
                        const float* __restrict__ Wo, float* __restrict__ t2) {
    __shared__ float sWr[C2 * C2], sWo[C2 * C2], sb[C2];
    __shared__ float sacc[2][128][21];   // +1 pad
    for (int k = threadIdx.x; k < C2 * C2; k += 256) { sWr[k] = Wr[k]; sWo[k] = Wo[k]; }
    if (threadIdx.x < C2) sb[threadIdx.x] = bb[threadIdx.x];
    int nl = threadIdx.x & 127;
    int half = threadIdx.x >> 7;          // wave-uniform
    int gn = blockIdx.x * 128 + nl;
    int m = cnt[gn]; if (m > CAP) m = CAP;
    int h0 = m >> 1;
    int lo = half ? h0 : 0;
    int hi = half ? m : h0;
    float acc[C2];
#pragma unroll
    for (int q = 0; q < C2; q++) acc[q] = 0.f;
    gather16(hnA, slots, gn, lo, hi, acc);        // phase A: ch 0-7
    gather16(hnB1, slots, gn, lo, hi, acc + 8);   // phase B1: ch 8-15
    gather8(hnB2, slots, gn, lo, hi, acc + 16);   // phase B2: ch 16-19
#pragma unroll
    for (int q = 0; q < C2; q++) sacc[half][nl][q] = acc[q];
    __syncthreads();
    // epilogue
    int n2 = threadIdx.x >> 1, oh = threadIdx.x & 1;
    int gn2 = blockIdx.x * 128 + n2;
    float accf[C2];
#pragma unroll
    for (int q = 0; q < C2; q++) accf[q] = sacc[0][n2][q] + sacc[1][n2][q];
    float h[C2];
    unp8(hnA[gn2], h); unp8(hnB1[gn2], h + 8); unp4(hnB2[gn2], h + 16);
    float outv[10];
#pragma unroll
    for (int jj = 0; jj < 10; jj++) {
        int j = oh * 10 + jj;
        float a = sb[j];
#pragma unroll
        for (int q = 0; q < C2; q++) a += accf[q] * sWr[q * C2 + j] + h[q] * sWo[q * C2 + j];
        outv[jj] = lrelu(a);
    }
#pragma unroll
    for (int jj = 0; jj < 10; jj++) t2[(size_t)gn2 * C2 + oh * 10 + jj] = outv[jj];
}

// ---------------- BN2 apply + project: y = h@W_rel3, r2 = h@W_root3 + b3 ----------------
__global__ void k_bn2_proj(const float* __restrict__ t, const float* __restrict__ mu,
                           const float* __restrict__ rs, const float* __restrict__ gam,
                           const float* __restrict__ bet, const float* __restrict__ Wr3,
                           const float* __restrict__ b3, const float* __restrict__ Wo3,
                           float* __restrict__ y, float* __restrict__ r2) {
    __shared__ float sWr[C2], sWo[C2];
    if (threadIdx.x < C2) { sWr[threadIdx.x] = Wr3[threadIdx.x]; sWo[threadIdx.x] = Wo3[threadIdx.x]; }
    __syncthreads();
    int n = blockIdx.x * 256 + threadIdx.x;
    if (n >= NTOT) return;
    int i = n & (N_NODES - 1);
    float sc = rs[i] * gam[i];
    float sh = bet[i] - mu[i] * sc;
    float v[C2];
    const float4* tp = (const float4*)(t + (size_t)n * C2);
#pragma unroll
    for (int q = 0; q < 5; q++) ((float4*)v)[q] = tp[q];
    float ay = 0.f, ar = 0.f;
#pragma unroll
    for (int j = 0; j < C2; j++) {
        float hv = v[j] * sc + sh;
        ay += hv * sWr[j];
        ar += hv * sWo[j];
    }
    y[n] = ay;
    r2[n] = ar + b3[0];
}

// ---------------- conv3: 2-way edge split, 128 nodes/block + per-graph partial stats ----------------
__global__ __launch_bounds__(256) void k_conv3(const float* __restrict__ y, const float* __restrict__ r2,
                        const unsigned* __restrict__ slots, const int* __restrict__ cnt,
                        float* __restrict__ hout, float* __restrict__ gsum, float* __restrict__ gss) {
    __shared__ float pbuf[2][128];
    __shared__ float ls[4], lss[4];
    int nl = threadIdx.x & 127;
    int half = threadIdx.x >> 7;          // wave-uniform
    int n = blockIdx.x * 128 + nl;
    int m = cnt[n]; if (m > CAP) m = CAP;
    int h0 = m >> 1;
    int lo = half ? h0 : 0;
    int hi = half ? m : h0;
    float a = 0.f;
    int i = lo;
    for (; i + 8 <= hi; i += 8) {
        unsigned p[8];
#pragma unroll
        for (int k = 0; k < 8; k++) p[k] = __builtin_nontemporal_load(slots + (size_t)(i + k) * NTOT + n);
#pragma unroll
        for (int k = 0; k < 8; k++) { int s; float w; unpack_edge(p[k], s, w); a += y[s] * w; }
    }
    for (; i < hi; i++) {
        unsigned p = __builtin_nontemporal_load(slots + (size_t)i * NTOT + n);
        int s; float w; unpack_edge(p, s, w);
        a += y[s] * w;
    }
    pbuf[half][nl] = a;
    __syncthreads();
    float v = 0.f;
    if (half == 0) {
        v = lrelu(pbuf[0][nl] + pbuf[1][nl] + r2[n]);
        hout[n] = v;
    }
    float s = v, ss = v * v;
#pragma unroll
    for (int o = 32; o > 0; o >>= 1) { s += __shfl_down(s, o); ss += __shfl_down(ss, o); }
    int wid = threadIdx.x >> 6, lid = threadIdx.x & 63;
    if (lid == 0) { ls[wid] = s; lss[wid] = ss; }
    __syncthreads();
    if (threadIdx.x == 0) {
        int g = blockIdx.x >> 5;   // 32 blocks of 128 nodes per graph
        atomicAdd(&gsum[g], ls[0] + ls[1] + ls[2] + ls[3]);
        atomicAdd(&gss[g], lss[0] + lss[1] + lss[2] + lss[3]);
    }
}

// ---------------- fc1 (per-graph stats folded in) ----------------
__global__ void k_fc1(const float* __restrict__ h, const float* __restrict__ gsum,
                      const float* __restrict__ gss, const float* __restrict__ W,
                      const float* __restrict__ b, float* __restrict__ z) {
    __shared__ float ls[4];
    int blk = blockIdx.x;
    int g = blk / 50, k = blk - g * 50;
    float mu = gsum[g] / N_NODES;
    float var = (gss[g] - N_NODES * mu * mu) / (N_NODES - 1);
    float inv = 1.f / (var + 1e-10f);   // reference divides by (var + eps), NOT std
    const float* hr = h + (size_t)g * N_NODES;
    float p = 0.f;
    for (int n = threadIdx.x; n < N_NODES; n += 256)
        p += (hr[n] - mu) * inv * W[(size_t)n * 50 + k];
#pragma unroll
    for (int off = 32; off > 0; off >>= 1) p += __shfl_down(p, off);
    int wid = threadIdx.x >> 6, lid = threadIdx.x & 63;
    if (lid == 0) ls[wid] = p;
    __syncthreads();
    if (threadIdx.x == 0) {
        float S = ls[0] + ls[1] + ls[2] + ls[3];
        z[g * 50 + k] = lrelu(S + b[k]);
    }
}

// ---------------- fc2 ----------------
__global__ void k_fc2(const float* __restrict__ z, const float* __restrict__ W,
                      const float* __restrict__ b, float* __restrict__ out) {
    int t = threadIdx.x;
    if (t >= N_GRAPHS * 2) return;
    int g = t >> 1, o = t & 1;
    float acc = b[o];
#pragma unroll
    for (int k = 0; k < 50; k++) acc += z[g * 50 + k] * W[k * 2 + o];
    out[g * 2 + o] = acc;
}

extern "C" void kernel_launch(void* const* d_in, const int* in_sizes, int n_in,
                              void* d_out, int out_size, void* d_ws, size_t ws_size,
                              hipStream_t stream) {
    const float* x    = (const float*)d_in[0];
    const int*   ei   = (const int*)d_in[1];
    const float* ea   = (const float*)d_in[2];
    const float* Wr1  = (const float*)d_in[3];
    const float* b1   = (const float*)d_in[4];
    const float* Wo1  = (const float*)d_in[5];
    const float* Wr2  = (const float*)d_in[6];
    const float* b2   = (const float*)d_in[7];
    const float* Wo2  = (const float*)d_in[8];
    const float* Wr3  = (const float*)d_in[9];
    const float* b3   = (const float*)d_in[10];
    const float* Wo3  = (const float*)d_in[11];
    const float* bn1g = (const float*)d_in[12];
    const float* bn1b = (const float*)d_in[13];
    const float* bn2g = (const float*)d_in[14];
    const float* bn2b = (const float*)d_in[15];
    const float* fc1W = (const float*)d_in[16];
    const float* fc1b = (const float*)d_in[17];
    const float* fc2W = (const float*)d_in[18];
    const float* fc2b = (const float*)d_in[19];
    float* out = (float*)d_out;

    // ---- workspace sizing ----
    const size_t part_bytes  = (size_t)NBUCK * CAPB * sizeof(uint2);         // 36.7 MB
    const size_t slots_bytes = (size_t)NTOT * CAP * sizeof(unsigned);        // 37.75 MB
    const size_t tail_bytes  = (size_t)NTOT * C2 * sizeof(float)             // bufA
                             + (size_t)NTOT * 16 * 4                         // xa + xb + hnA + hnB1
                             + (size_t)NTOT * 8                              // hnB2
                             + (size_t)NTOT * 2 * sizeof(float)              // y, r2
                             + (size_t)NTOT * sizeof(int)                    // cnt
                             + (size_t)(NBUCK + 4 * N_NODES + 8 * N_GRAPHS + N_GRAPHS * 50 + 64) * sizeof(float);
    const bool useSort = ws_size >= part_bytes + slots_bytes + tail_bytes;   // tier 1 (else slot-fill)

    char* wsb = (char*)d_ws;
    uint2*    part  = (uint2*)wsb;     wsb += useSort ? part_bytes : 0;
    unsigned* slots = (unsigned*)wsb;  wsb += slots_bytes;
    float*    bufA  = (float*)wsb;     wsb += (size_t)NTOT * C2 * sizeof(float);
    uint4*    xa    = (uint4*)wsb;     wsb += (size_t)NTOT * 16;
    uint4*    xb    = (uint4*)wsb;     wsb += (size_t)NTOT * 16;
    uint4*    hnA   = (uint4*)wsb;     wsb += (size_t)NTOT * 16;
    uint4*    hnB1  = (uint4*)wsb;     wsb += (size_t)NTOT * 16;
    uint2*    hnB2  = (uint2*)wsb;     wsb += (size_t)NTOT * 8;
    float*    yv    = (float*)wsb;     wsb += (size_t)NTOT * sizeof(float);
    float*    r2v   = (float*)wsb;     wsb += (size_t)NTOT * sizeof(float);
    int*      cnt   = (int*)wsb;       wsb += (size_t)NTOT * sizeof(int);
    int*      gcur  = (int*)wsb;       wsb += NBUCK * sizeof(int);
    float*    mu1   = (float*)wsb;     wsb += N_NODES * sizeof(float);
    float*    rs1   = (float*)wsb;     wsb += N_NODES * sizeof(float);
    float*    mu2   = (float*)wsb;     wsb += N_NODES * sizeof(float);
    float*    rs2   = (float*)wsb;     wsb += N_NODES * sizeof(float);
    float*    gsum  = (float*)wsb;     wsb += N_GRAPHS * sizeof(float);
    float*    gss   = (float*)wsb;     wsb += N_GRAPHS * sizeof(float);
    float*    z     = (float*)wsb;     wsb += N_GRAPHS * 50 * sizeof(float);

    const int EB = (NE + 255) / 256;     // 16384
    const int NB = (NTOT + 255) / 256;   // 512

    // ---- build + x cast (every call; ws is re-poisoned) ----
    hipMemsetAsync(gsum, 0, 2 * N_GRAPHS * sizeof(float), stream);
    k_xcast<<<NB, 256, 0, stream>>>(x, xa, xb);
    if (useSort) {
        hipMemsetAsync(gcur, 0, NBUCK * sizeof(int), stream);
        k_part1<<<NE / EPB1, 256, 0, stream>>>(ei, ea, gcur, part);
        k_part2<<<NBUCK * 2, 256, 0, stream>>>(gcur, part, slots, cnt);
    } else {
        hipMemsetAsync(cnt, 0, (size_t)NTOT * sizeof(int), stream);
        k_fill_slots<<<EB, 256, 0, stream>>>(ei, ea, cnt, slots);
    }

    // ---- conv1 + BN1 ----
    k_conv1<<<NTOT / 128, 256, 0, stream>>>(xa, xb, slots, cnt, Wr1, b1, Wo1, bufA);
    k_stats<<<N_NODES, 64, 0, stream>>>(bufA, mu1, rs1);
    k_bn_apply<<<NB, 256, 0, stream>>>(bufA, mu1, rs1, bn1g, bn1b, hnA, hnB1, hnB2);

    // ---- conv2 + BN2 + projection; t2 reuses bufA ----
    k_conv2<<<NTOT / 128, 256, 0, stream>>>(hnA, hnB1, hnB2, slots, cnt, Wr2, b2, Wo2, bufA);
    k_stats<<<N_NODES, 64, 0, stream>>>(bufA, mu2, rs2);
    k_bn2_proj<<<NB, 256, 0, stream>>>(bufA, mu2, rs2, bn2g, bn2b, Wr3, b3, Wo3, yv, r2v);

    // ---- conv3 (scalar gather) + per-graph partial stats ----
    k_conv3<<<NTOT / 128, 256, 0, stream>>>(yv, r2v, slots, cnt, out + 64, gsum, gss);

    // ---- FC head ----
    k_fc1<<<N_GRAPHS * 50, 256, 0, stream>>>(out + 64, gsum, gss, fc1W, fc1b, z);
    k_fc2<<<1, 64, 0, stream>>>(z, fc2W, fc2b, out);
}

// Round 9
// 433.117 us; speedup vs baseline: 1.1837x; 1.1837x over previous
//
#include <hip/hip_runtime.h>
#include <hip/hip_fp16.h>

#define N_NODES 4096
#define N_GRAPHS 32
#define NTOT (N_NODES * N_GRAPHS)   // 131072
#define NE (NTOT * 32)              // 4194304 edges
#define C1 16
#define C2 20
#define CAP 72                       // max in-degree capacity (Poisson(32) tail @72 ~5e-10/node)

// bucket-sort build parameters
#define NBUCK 512                    // dst buckets (256 nodes each)
#define BSHIFT 8
#define BMASK 255
#define CAPB 8960                    // records per bucket region (mean 8192, +8.5 sigma)
#define EPB1 8192                    // edges per pass-1 block (512 blocks total)

__device__ __forceinline__ float lrelu(float v) { return v > 0.f ? v : 0.01f * v; }

// ---- edge pack: src (17 bits) | w quantized to 15-bit fixed point in [0,1) ----
__device__ __forceinline__ unsigned pack_edge(int src, float w) {
    int k = __float2int_rn(w * 32768.f);
    if (k > 32767) k = 32767;
    return (unsigned)src | ((unsigned)k << 17);
}
__device__ __forceinline__ void unpack_edge(unsigned p, int& src, float& w) {
    src = (int)(p & 0x1FFFFu);
    w = (float)(p >> 17) * 3.0517578125e-5f;   // /32768
}

// ---- fp16 pack/unpack/fma helpers ----
__device__ __forceinline__ uint4 pack8h(const float* v) {
    union { uint4 u4; __half h[8]; } c;
#pragma unroll
    for (int q = 0; q < 8; q++) c.h[q] = __float2half(v[q]);
    return c.u4;
}
__device__ __forceinline__ uint2 pack4h(const float* v) {
    union { uint2 u2; __half h[4]; } c;
#pragma unroll
    for (int q = 0; q < 4; q++) c.h[q] = __float2half(v[q]);
    return c.u2;
}
__device__ __forceinline__ void fma8(uint4 u, float wv, float* acc) {
    union { uint4 u4; __half2 h2[4]; } c; c.u4 = u;
#pragma unroll
    for (int q = 0; q < 4; q++) {
        float2 f = __half22float2(c.h2[q]);
        acc[2 * q]     += f.x * wv;
        acc[2 * q + 1] += f.y * wv;
    }
}
__device__ __forceinline__ void fma4(uint2 u, float wv, float* acc) {
    union { uint2 u2; __half2 h2[2]; } c; c.u2 = u;
#pragma unroll
    for (int q = 0; q < 2; q++) {
        float2 f = __half22float2(c.h2[q]);
        acc[2 * q]     += f.x * wv;
        acc[2 * q + 1] += f.y * wv;
    }
}
__device__ __forceinline__ void unp8(uint4 u, float* v) {
    union { uint4 u4; __half2 h2[4]; } c; c.u4 = u;
#pragma unroll
    for (int q = 0; q < 4; q++) {
        float2 f = __half22float2(c.h2[q]);
        v[2 * q] = f.x; v[2 * q + 1] = f.y;
    }
}
__device__ __forceinline__ void unp4(uint2 u, float* v) {
    union { uint2 u2; __half2 h2[2]; } c; c.u2 = u;
#pragma unroll
    for (int q = 0; q < 2; q++) {
        float2 f = __half22float2(c.h2[q]);
        v[2 * q] = f.x; v[2 * q + 1] = f.y;
    }
}

// ======================= build pass 1: LDS counting sort per 8192-edge tile (R8, kept) =======================
__global__ __launch_bounds__(256) void k_part1(const int* __restrict__ ei,
                                               const float* __restrict__ ea,
                                               int* __restrict__ gcur,
                                               uint2* __restrict__ part) {
    __shared__ unsigned lrecA[EPB1];          // packed (src|w)      32 KB
    __shared__ unsigned char lrecB[EPB1];     // local dst (8 bits)   8 KB
    __shared__ int hist[NBUCK], sscan[NBUCK], base[NBUCK], lcur[NBUCK];  // 8 KB
    __shared__ int ts[256];                   // 1 KB
    int t = threadIdx.x;
    hist[t] = 0; hist[t + 256] = 0;
    __syncthreads();
    int eb = blockIdx.x * EPB1;
    int dreg[EPB1 / 256];
#pragma unroll
    for (int i = 0; i < EPB1 / 256; i++) {
        int d = ei[NE + eb + i * 256 + t];
        dreg[i] = d;
        atomicAdd(&hist[d >> BSHIFT], 1);
    }
    __syncthreads();
    int a0 = hist[2 * t], a1 = hist[2 * t + 1];
    ts[t] = a0 + a1;
    __syncthreads();
    for (int d = 1; d < 256; d <<= 1) {
        int v = (t >= d) ? ts[t - d] : 0;
        __syncthreads();
        ts[t] += v;
        __syncthreads();
    }
    int excl = (t == 0) ? 0 : ts[t - 1];
    sscan[2 * t] = excl;
    sscan[2 * t + 1] = excl + a0;
    lcur[2 * t] = excl;
    lcur[2 * t + 1] = excl + a0;
    base[t]       = atomicAdd(&gcur[t], hist[t]);
    base[t + 256] = atomicAdd(&gcur[t + 256], hist[t + 256]);
    __syncthreads();
#pragma unroll
    for (int i = 0; i < EPB1 / 256; i++) {
        int e = eb + i * 256 + t;
        int d = dreg[i];
        int b = d >> BSHIFT;
        int pos = atomicAdd(&lcur[b], 1);
        lrecA[pos] = pack_edge(ei[e], ea[3 * e + 2]);
        lrecB[pos] = (unsigned char)(d & BMASK);
    }
    __syncthreads();
    for (int j = t; j < EPB1; j += 256) {
        int lo = 0, hi = NBUCK - 1;
        while (lo < hi) { int mid = (lo + hi + 1) >> 1; if (sscan[mid] <= j) lo = mid; else hi = mid - 1; }
        int b = lo;
        int dp = base[b] + (j - sscan[b]);
        if (dp < CAPB) part[(size_t)b * CAPB + dp] = make_uint2(lrecA[j], (unsigned)lrecB[j]);
    }
}

// ======================= build pass 2: LDS tile + coalesced slot writes (R8, kept) =======================
__global__ __launch_bounds__(256) void k_part2(const int* __restrict__ gcur,
                                               const uint2* __restrict__ part,
                                               unsigned* __restrict__ slots,
                                               int* __restrict__ cnt) {
    __shared__ unsigned tile[128 * CAP];      // 36.9 KB, layout [pos][l]
    __shared__ int cur[128];
    __shared__ int maxc;
    int t = threadIdx.x;
    if (t < 128) cur[t] = 0;
    if (t == 0) maxc = 0;
    __syncthreads();
    int b = blockIdx.x >> 1;
    int halfsel = blockIdx.x & 1;
    int nbase = (b << BSHIFT) + (halfsel << 7);
    int nrec = gcur[b]; if (nrec > CAPB) nrec = CAPB;
    const uint2* rp = part + (size_t)b * CAPB;
    for (int i = t; i < nrec; i += 256) {
        uint2 r = rp[i];
        int ld = (int)r.y;
        if ((ld >> 7) == halfsel) {
            int l = ld & 127;
            int pos = atomicAdd(&cur[l], 1);
            if (pos < CAP) tile[pos * 128 + l] = r.x;
        }
    }
    __syncthreads();
    if (t < 128) { cnt[nbase + t] = cur[t]; atomicMax(&maxc, cur[t]); }
    __syncthreads();
    int mc = maxc; if (mc > CAP) mc = CAP;
    for (int j = t; j < mc * 128; j += 256) {
        int pos = j >> 7, l = j & 127;
        slots[(size_t)pos * NTOT + nbase + l] = tile[j];
    }
}

// ======================= fallback build: single-atomic slot fill =======================
__global__ void k_fill_slots(const int* __restrict__ ei, const float* __restrict__ ea,
                             int* __restrict__ cnt, unsigned* __restrict__ slots) {
    int e = blockIdx.x * 256 + threadIdx.x;
    if (e >= NE) return;
    int d = ei[NE + e];
    int pos = atomicAdd(&cnt[d], 1);
    if (pos < CAP) slots[(size_t)pos * NTOT + d] = pack_edge(ei[e], ea[3 * e + 2]);
}

// ---------------- x -> fp16 split arrays (ch0-7, ch8-15) ----------------
__global__ void k_xcast(const float* __restrict__ x, uint4* __restrict__ xa, uint4* __restrict__ xb) {
    int n = blockIdx.x * 256 + threadIdx.x;
    if (n >= NTOT) return;
    float xr[C1];
    const float4* xp = (const float4*)(x + (size_t)n * C1);
#pragma unroll
    for (int q = 0; q < 4; q++) ((float4*)xr)[q] = xp[q];
    xa[n] = pack8h(xr);
    xb[n] = pack8h(xr + 8);
}

// ---------------- conv1 (R6 structure): two sequential L2-resident gather phases + GEMM ----------------
__global__ __launch_bounds__(256) void k_conv1(const float* __restrict__ x,
                        const uint4* __restrict__ xa, const uint4* __restrict__ xb,
                        const unsigned* __restrict__ slots, const int* __restrict__ cnt,
                        const float* __restrict__ Wr, const float* __restrict__ bb,
                        const float* __restrict__ Wo, float* __restrict__ t1) {
    __shared__ float sWr[C1 * C2], sWo[C1 * C2], sb[C2];
    for (int k = threadIdx.x; k < C1 * C2; k += 256) { sWr[k] = Wr[k]; sWo[k] = Wo[k]; }
    if (threadIdx.x < C2) sb[threadIdx.x] = bb[threadIdx.x];
    __syncthreads();
    int n = blockIdx.x * 256 + threadIdx.x;
    int m = cnt[n]; if (m > CAP) m = CAP;
    float acc[C1];
#pragma unroll
    for (int i = 0; i < C1; i++) acc[i] = 0.f;
    // ---- phase A: channels 0-7 (xa, 2.1 MB working set) ----
    {
        int i = 0;
        for (; i + 4 <= m; i += 4) {
            unsigned p0 = __builtin_nontemporal_load(slots + (size_t)(i + 0) * NTOT + n);
            unsigned p1 = __builtin_nontemporal_load(slots + (size_t)(i + 1) * NTOT + n);
            unsigned p2 = __builtin_nontemporal_load(slots + (size_t)(i + 2) * NTOT + n);
            unsigned p3 = __builtin_nontemporal_load(slots + (size_t)(i + 3) * NTOT + n);
            int s0, s1, s2, s3; float w0, w1, w2, w3;
            unpack_edge(p0, s0, w0); unpack_edge(p1, s1, w1);
            unpack_edge(p2, s2, w2); unpack_edge(p3, s3, w3);
            uint4 u0 = xa[s0], u1 = xa[s1], u2 = xa[s2], u3 = xa[s3];
            fma8(u0, w0, acc); fma8(u1, w1, acc); fma8(u2, w2, acc); fma8(u3, w3, acc);
        }
        for (; i < m; i++) {
            unsigned p = __builtin_nontemporal_load(slots + (size_t)i * NTOT + n);
            int s; float w; unpack_edge(p, s, w);
            fma8(xa[s], w, acc);
        }
    }
    // ---- phase B: channels 8-15 (xb) ----
    {
        int i = 0;
        for (; i + 4 <= m; i += 4) {
            unsigned p0 = __builtin_nontemporal_load(slots + (size_t)(i + 0) * NTOT + n);
            unsigned p1 = __builtin_nontemporal_load(slots + (size_t)(i + 1) * NTOT + n);
            unsigned p2 = __builtin_nontemporal_load(slots + (size_t)(i + 2) * NTOT + n);
            unsigned p3 = __builtin_nontemporal_load(slots + (size_t)(i + 3) * NTOT + n);
            int s0, s1, s2, s3; float w0, w1, w2, w3;
            unpack_edge(p0, s0, w0); unpack_edge(p1, s1, w1);
            unpack_edge(p2, s2, w2); unpack_edge(p3, s3, w3);
            uint4 u0 = xb[s0], u1 = xb[s1], u2 = xb[s2], u3 = xb[s3];
            fma8(u0, w0, acc + 8); fma8(u1, w1, acc + 8); fma8(u2, w2, acc + 8); fma8(u3, w3, acc + 8);
        }
        for (; i < m; i++) {
            unsigned p = __builtin_nontemporal_load(slots + (size_t)i * NTOT + n);
            int s; float w; unpack_edge(p, s, w);
            fma8(xb[s], w, acc + 8);
        }
    }
    float xr[C1];
    const float4* xp = (const float4*)(x + (size_t)n * C1);
#pragma unroll
    for (int q = 0; q < 4; q++) ((float4*)xr)[q] = xp[q];
    float outv[C2];
#pragma unroll
    for (int j = 0; j < C2; j++) {
        float a = sb[j];
#pragma unroll
        for (int i = 0; i < C1; i++) a += acc[i] * sWr[i * C2 + j] + xr[i] * sWo[i * C2 + j];
        outv[j] = lrelu(a);
    }
    float4* op = (float4*)(t1 + (size_t)n * C2);
#pragma unroll
    for (int q = 0; q < 5; q++) op[q] = ((float4*)outv)[q];
}

// ---------------- BN stats: per node-index i over 32 graphs x 20 ch (fp32 t) ----------------
__global__ void k_stats(const float* __restrict__ t, float* __restrict__ mu, float* __restrict__ rs) {
    int i = blockIdx.x;
    float s = 0.f, ss = 0.f;
    for (int k = threadIdx.x; k < N_GRAPHS * C2; k += 64) {
        int g = k / C2, j = k - g * C2;
        float v = t[((size_t)(g * N_NODES + i)) * C2 + j];
        s += v; ss += v * v;
    }
#pragma unroll
    for (int off = 32; off > 0; off >>= 1) { s += __shfl_down(s, off); ss += __shfl_down(ss, off); }
    if (threadIdx.x == 0) {
        float m = s * (1.f / (N_GRAPHS * C2));
        float var = ss * (1.f / (N_GRAPHS * C2)) - m * m;
        mu[i] = m;
        rs[i] = rsqrtf(var + 1e-5f);
    }
}

// ---------------- BN apply -> fp16 split hn: hnA ch0-7 (16B), hnB ch8-19 (24B rows) ----------------
__global__ void k_bn_apply(const float* __restrict__ t, const float* __restrict__ mu,
                           const float* __restrict__ rs, const float* __restrict__ gam,
                           const float* __restrict__ bet, uint4* __restrict__ hnA,
                           uint2* __restrict__ hnB) {
    int n = blockIdx.x * 256 + threadIdx.x;
    if (n >= NTOT) return;
    int i = n & (N_NODES - 1);
    float sc = rs[i] * gam[i];
    float sh = bet[i] - mu[i] * sc;
    float v[C2];
    const float4* tp = (const float4*)(t + (size_t)n * C2);
#pragma unroll
    for (int q = 0; q < 5; q++) ((float4*)v)[q] = tp[q];
#pragma unroll
    for (int j = 0; j < C2; j++) v[j] = v[j] * sc + sh;
    hnA[n] = pack8h(v);
    uint2* hp = hnB + (size_t)n * 3;
    hp[0] = pack4h(v + 8);
    hp[1] = pack4h(v + 12);
    hp[2] = pack4h(v + 16);
}

// ---------------- conv2 (R6 structure): two sequential phases (hnA 2.1 MB, hnB 3.1 MB) ----------------
__global__ __launch_bounds__(256) void k_conv2(const uint4* __restrict__ hnA,
                        const uint2* __restrict__ hnB,
                        const unsigned* __restrict__ slots, const int* __restrict__ cnt,
                        const float* __restrict__ Wr, const float* __restrict__ bb,
                        const float* __restrict__ Wo, float* __restrict__ t2) {
    __shared__ float sWr[C2 * C2], sWo[C2 * C2], sb[C2];
    for (int k = threadIdx.x; k < C2 * C2; k += 256) { sWr[k] = Wr[k]; sWo[k] = Wo[k]; }
    if (threadIdx.x < C2) sb[threadIdx.x] = bb[threadIdx.x];
    __syncthreads();
    int n = blockIdx.x * 256 + threadIdx.x;
    int m = cnt[n]; if (m > CAP) m = CAP;
    float acc[C2];
#pragma unroll
    for (int i = 0; i < C2; i++) acc[i] = 0.f;
    // ---- phase A: channels 0-7 (hnA) ----
    {
        int i = 0;
        for (; i + 4 <= m; i += 4) {
            unsigned p0 = __builtin_nontemporal_load(slots + (size_t)(i + 0) * NTOT + n);
            unsigned p1 = __builtin_nontemporal_load(slots + (size_t)(i + 1) * NTOT + n);
            unsigned p2 = __builtin_nontemporal_load(slots + (size_t)(i + 2) * NTOT + n);
            unsigned p3 = __builtin_nontemporal_load(slots + (size_t)(i + 3) * NTOT + n);
            int s0, s1, s2, s3; float w0, w1, w2, w3;
            unpack_edge(p0, s0, w0); unpack_edge(p1, s1, w1);
            unpack_edge(p2, s2, w2); unpack_edge(p3, s3, w3);
            uint4 u0 = hnA[s0], u1 = hnA[s1], u2 = hnA[s2], u3 = hnA[s3];
            fma8(u0, w0, acc); fma8(u1, w1, acc); fma8(u2, w2, acc); fma8(u3, w3, acc);
        }
        for (; i < m; i++) {
            unsigned p = __builtin_nontemporal_load(slots + (size_t)i * NTOT + n);
            int s; float w; unpack_edge(p, s, w);
            fma8(hnA[s], w, acc);
        }
    }
    // ---- phase B: channels 8-19 (hnB, 24 B rows) ----
    {
        int i = 0;
        for (; i + 4 <= m; i += 4) {
            unsigned p0 = __builtin_nontemporal_load(slots + (size_t)(i + 0) * NTOT + n);
            unsigned p1 = __builtin_nontemporal_load(slots + (size_t)(i + 1) * NTOT + n);
            unsigned p2 = __builtin_nontemporal_load(slots + (size_t)(i + 2) * NTOT + n);
            unsigned p3 = __builtin_nontemporal_load(slots + (size_t)(i + 3) * NTOT + n);
            int s0, s1, s2, s3; float w0, w1, w2, w3;
            unpack_edge(p0, s0, w0); unpack_edge(p1, s1, w1);
            unpack_edge(p2, s2, w2); unpack_edge(p3, s3, w3);
            const uint2* r0 = hnB + (size_t)s0 * 3;
            const uint2* r1 = hnB + (size_t)s1 * 3;
            const uint2* r2 = hnB + (size_t)s2 * 3;
            const uint2* r3 = hnB + (size_t)s3 * 3;
            uint2 a0 = r0[0], b0 = r0[1], c0 = r0[2];
            uint2 a1 = r1[0], b1 = r1[1], c1 = r1[2];
            uint2 a2 = r2[0], b2 = r2[1], c2 = r2[2];
            uint2 a3 = r3[0], b3 = r3[1], c3 = r3[2];
            fma4(a0, w0, acc + 8); fma4(b0, w0, acc + 12); fma4(c0, w0, acc + 16);
            fma4(a1, w1, acc + 8); fma4(b1, w1, acc + 12); fma4(c1, w1, acc + 16);
            fma4(a2, w2, acc + 8); fma4(b2, w2, acc + 12); fma4(c2, w2, acc + 16);
            fma4(a3, w3, acc + 8); fma4(b3, w3, acc + 12); fma4(c3, w3, acc + 16);
        }
        for (; i < m; i++) {
            unsigned p = __builtin_nontemporal_load(slots + (size_t)i * NTOT + n);
            int s; float w; unpack_edge(p, s, w);
            const uint2* r = hnB + (size_t)s * 3;
            fma4(r[0], w, acc + 8); fma4(r[1], w, acc + 12); fma4(r[2], w, acc + 16);
        }
    }
    // root term
    float h[C2];
    unp8(hnA[n], h);
    {
        const uint2* r = hnB + (size_t)n * 3;
        unp4(r[0], h + 8); unp4(r[1], h + 12); unp4(r[2], h + 16);
    }
    float outv[C2];
#pragma unroll
    for (int j = 0; j < C2; j++) {
        float a = sb[j];
#pragma unroll
        for (int i = 0; i < C2; i++) a += acc[i] * sWr[i * C2 + j] + h[i] * sWo[i * C2 + j];
        outv[j] = lrelu(a);
    }
    float4* op = (float4*)(t2 + (size_t)n * C2);
#pragma unroll
    for (int q = 0; q < 5; q++) op[q] = ((float4*)outv)[q];
}

// ---------------- BN2 apply + project: y = h@W_rel3, r2 = h@W_root3 + b3 ----------------
__global__ void k_bn2_proj(const float* __restrict__ t, const float* __restrict__ mu,
                           const float* __restrict__ rs, const float* __restrict__ gam,
                           const float* __restrict__ bet, const float* __restrict__ Wr3,
                           const float* __restrict__ b3, const float* __restrict__ Wo3,
                           float* __restrict__ y, float* __restrict__ r2) {
    __shared__ float sWr[C2], sWo[C2];
    if (threadIdx.x < C2) { sWr[threadIdx.x] = Wr3[threadIdx.x]; sWo[threadIdx.x] = Wo3[threadIdx.x]; }
    __syncthreads();
    int n = blockIdx.x * 256 + threadIdx.x;
    if (n >= NTOT) return;
    int i = n & (N_NODES - 1);
    float sc = rs[i] * gam[i];
    float sh = bet[i] - mu[i] * sc;
    float v[C2];
    const float4* tp = (const float4*)(t + (size_t)n * C2);
#pragma unroll
    for (int q = 0; q < 5; q++) ((float4*)v)[q] = tp[q];
    float ay = 0.f, ar = 0.f;
#pragma unroll
    for (int j = 0; j < C2; j++) {
        float hv = v[j] * sc + sh;
        ay += hv * sWr[j];
        ar += hv * sWo[j];
    }
    y[n] = ay;
    r2[n] = ar + b3[0];
}

// ---------------- conv3 (R6 structure): scalar gather (y 524 KB) + lrelu + per-graph stats ----------------
__global__ __launch_bounds__(256) void k_conv3(const float* __restrict__ y, const float* __restrict__ r2,
                        const unsigned* __restrict__ slots, const int* __restrict__ cnt,
                        float* __restrict__ hout, float* __restrict__ gsum, float* __restrict__ gss) {
    __shared__ float ls[4], lss[4];
    int n = blockIdx.x * 256 + threadIdx.x;
    int m = cnt[n]; if (m > CAP) m = CAP;
    float a = 0.f;
    int i = 0;
    for (; i + 4 <= m; i += 4) {
        unsigned p0 = __builtin_nontemporal_load(slots + (size_t)(i + 0) * NTOT + n);
        unsigned p1 = __builtin_nontemporal_load(slots + (size_t)(i + 1) * NTOT + n);
        unsigned p2 = __builtin_nontemporal_load(slots + (size_t)(i + 2) * NTOT + n);
        unsigned p3 = __builtin_nontemporal_load(slots + (size_t)(i + 3) * NTOT + n);
        int s0, s1, s2, s3; float w0, w1, w2, w3;
        unpack_edge(p0, s0, w0); unpack_edge(p1, s1, w1);
        unpack_edge(p2, s2, w2); unpack_edge(p3, s3, w3);
        a += y[s0] * w0 + y[s1] * w1 + y[s2] * w2 + y[s3] * w3;
    }
    for (; i < m; i++) {
        unsigned p = __builtin_nontemporal_load(slots + (size_t)i * NTOT + n);
        int s; float w; unpack_edge(p, s, w);
        a += y[s] * w;
    }
    float v = lrelu(a + r2[n]);
    hout[n] = v;
    float s = v, ss = v * v;
#pragma unroll
    for (int o = 32; o > 0; o >>= 1) { s += __shfl_down(s, o); ss += __shfl_down(ss, o); }
    int wid = threadIdx.x >> 6, lid = threadIdx.x & 63;
    if (lid == 0) { ls[wid] = s; lss[wid] = ss; }
    __syncthreads();
    if (threadIdx.x == 0) {
        int g = blockIdx.x >> 4;   // 16 blocks of 256 per graph of 4096
        atomicAdd(&gsum[g], ls[0] + ls[1] + ls[2] + ls[3]);
        atomicAdd(&gss[g], lss[0] + lss[1] + lss[2] + lss[3]);
    }
}

// ---------------- fc1 (per-graph stats folded in) ----------------
__global__ void k_fc1(const float* __restrict__ h, const float* __restrict__ gsum,
                      const float* __restrict__ gss, const float* __restrict__ W,
                      const float* __restrict__ b, float* __restrict__ z) {
    __shared__ float ls[4];
    int blk = blockIdx.x;
    int g = blk / 50, k = blk - g * 50;
    float mu = gsum[g] / N_NODES;
    float var = (gss[g] - N_NODES * mu * mu) / (N_NODES - 1);
    float inv = 1.f / (var + 1e-10f);   // reference divides by (var + eps), NOT std
    const float* hr = h + (size_t)g * N_NODES;
    float p = 0.f;
    for (int n = threadIdx.x; n < N_NODES; n += 256)
        p += (hr[n] - mu) * inv * W[(size_t)n * 50 + k];
#pragma unroll
    for (int off = 32; off > 0; off >>= 1) p += __shfl_down(p, off);
    int wid = threadIdx.x >> 6, lid = threadIdx.x & 63;
    if (lid == 0) ls[wid] = p;
    __syncthreads();
    if (threadIdx.x == 0) {
        float S = ls[0] + ls[1] + ls[2] + ls[3];
        z[g * 50 + k] = lrelu(S + b[k]);
    }
}

// ---------------- fc2 ----------------
__global__ void k_fc2(const float* __restrict__ z, const float* __restrict__ W,
                      const float* __restrict__ b, float* __restrict__ out) {
    int t = threadIdx.x;
    if (t >= N_GRAPHS * 2) return;
    int g = t >> 1, o = t & 1;
    float acc = b[o];
#pragma unroll
    for (int k = 0; k < 50; k++) acc += z[g * 50 + k] * W[k * 2 + o];
    out[g * 2 + o] = acc;
}

extern "C" void kernel_launch(void* const* d_in, const int* in_sizes, int n_in,
                              void* d_out, int out_size, void* d_ws, size_t ws_size,
                              hipStream_t stream) {
    const float* x    = (const float*)d_in[0];
    const int*   ei   = (const int*)d_in[1];
    const float* ea   = (const float*)d_in[2];
    const float* Wr1  = (const float*)d_in[3];
    const float* b1   = (const float*)d_in[4];
    const float* Wo1  = (const float*)d_in[5];
    const float* Wr2  = (const float*)d_in[6];
    const float* b2   = (const float*)d_in[7];
    const float* Wo2  = (const float*)d_in[8];
    const float* Wr3  = (const float*)d_in[9];
    const float* b3   = (const float*)d_in[10];
    const float* Wo3  = (const float*)d_in[11];
    const float* bn1g = (const float*)d_in[12];
    const float* bn1b = (const float*)d_in[13];
    const float* bn2g = (const float*)d_in[14];
    const float* bn2b = (const float*)d_in[15];
    const float* fc1W = (const float*)d_in[16];
    const float* fc1b = (const float*)d_in[17];
    const float* fc2W = (const float*)d_in[18];
    const float* fc2b = (const float*)d_in[19];
    float* out = (float*)d_out;

    // ---- workspace sizing ----
    const size_t part_bytes  = (size_t)NBUCK * CAPB * sizeof(uint2);         // 36.7 MB
    const size_t slots_bytes = (size_t)NTOT * CAP * sizeof(unsigned);        // 37.75 MB
    const size_t tail_bytes  = (size_t)NTOT * C2 * sizeof(float)             // bufA
                             + (size_t)NTOT * 16 * 3                         // xa + xb + hnA
                             + (size_t)NTOT * 24                             // hnB
                             + (size_t)NTOT * 2 * sizeof(float)              // y, r2
                             + (size_t)NTOT * sizeof(int)                    // cnt
                             + (size_t)(NBUCK + 4 * N_NODES + 8 * N_GRAPHS + N_GRAPHS * 50 + 64) * sizeof(float);
    const bool useSort = ws_size >= part_bytes + slots_bytes + tail_bytes;   // tier 1 (else slot-fill)

    char* wsb = (char*)d_ws;
    uint2*    part  = (uint2*)wsb;     wsb += useSort ? part_bytes : 0;
    unsigned* slots = (unsigned*)wsb;  wsb += slots_bytes;
    float*    bufA  = (float*)wsb;     wsb += (size_t)NTOT * C2 * sizeof(float);
    uint4*    xa    = (uint4*)wsb;     wsb += (size_t)NTOT * 16;
    uint4*    xb    = (uint4*)wsb;     wsb += (size_t)NTOT * 16;
    uint4*    hnA   = (uint4*)wsb;     wsb += (size_t)NTOT * 16;
    uint2*    hnB   = (uint2*)wsb;     wsb += (size_t)NTOT * 24;
    float*    yv    = (float*)wsb;     wsb += (size_t)NTOT * sizeof(float);
    float*    r2v   = (float*)wsb;     wsb += (size_t)NTOT * sizeof(float);
    int*      cnt   = (int*)wsb;       wsb += (size_t)NTOT * sizeof(int);
    int*      gcur  = (int*)wsb;       wsb += NBUCK * sizeof(int);
    float*    mu1   = (float*)wsb;     wsb += N_NODES * sizeof(float);
    float*    rs1   = (float*)wsb;     wsb += N_NODES * sizeof(float);
    float*    mu2   = (float*)wsb;     wsb += N_NODES * sizeof(float);
    float*    rs2   = (float*)wsb;     wsb += N_NODES * sizeof(float);
    float*    gsum  = (float*)wsb;     wsb += N_GRAPHS * sizeof(float);
    float*    gss   = (float*)wsb;     wsb += N_GRAPHS * sizeof(float);
    float*    z     = (float*)wsb;     wsb += N_GRAPHS * 50 * sizeof(float);

    const int EB = (NE + 255) / 256;     // 16384
    const int NB = (NTOT + 255) / 256;   // 512

    // ---- build + x cast (every call; ws is re-poisoned) ----
    hipMemsetAsync(gsum, 0, 2 * N_GRAPHS * sizeof(float), stream);
    k_xcast<<<NB, 256, 0, stream>>>(x, xa, xb);
    if (useSort) {
        hipMemsetAsync(gcur, 0, NBUCK * sizeof(int), stream);
        k_part1<<<NE / EPB1, 256, 0, stream>>>(ei, ea, gcur, part);
        k_part2<<<NBUCK * 2, 256, 0, stream>>>(gcur, part, slots, cnt);
    } else {
        hipMemsetAsync(cnt, 0, (size_t)NTOT * sizeof(int), stream);
        k_fill_slots<<<EB, 256, 0, stream>>>(ei, ea, cnt, slots);
    }

    // ---- conv1 + BN1 ----
    k_conv1<<<NB, 256, 0, stream>>>(x, xa, xb, slots, cnt, Wr1, b1, Wo1, bufA);
    k_stats<<<N_NODES, 64, 0, stream>>>(bufA, mu1, rs1);
    k_bn_apply<<<NB, 256, 0, stream>>>(bufA, mu1, rs1, bn1g, bn1b, hnA, hnB);

    // ---- conv2 + BN2 + projection; t2 reuses bufA ----
    k_conv2<<<NB, 256, 0, stream>>>(hnA, hnB, slots, cnt, Wr2, b2, Wo2, bufA);
    k_stats<<<N_NODES, 64, 0, stream>>>(bufA, mu2, rs2);
    k_bn2_proj<<<NB, 256, 0, stream>>>(bufA, mu2, rs2, bn2g, bn2b, Wr3, b3, Wo3, yv, r2v);

    // ---- conv3 (scalar gather) + per-graph partial stats ----
    k_conv3<<<NB, 256, 0, stream>>>(yv, r2v, slots, cnt, out + 64, gsum, gss);

    // ---- FC head ----
    k_fc1<<<N_GRAPHS * 50, 256, 0, stream>>>(out + 64, gsum, gss, fc1W, fc1b, z);
    k_fc2<<<1, 64, 0, stream>>>(z, fc2W, fc2b, out);
}